// Round 3
// baseline (1731.877 us; speedup 1.0000x reference)
//
#include <hip/hip_runtime.h>

// Problem constants (MultiHeadAttention_79431125172249)
// All float tensors are fp32 (reference dtype); mask is int32; output fp32.
#define B_  32
#define S_  4096
#define E_  1024
#define H_  16
#define D_  64
#define NV_ 64
#define HD_ 1024   // H_*D_

typedef unsigned short ushort_t;
typedef __attribute__((ext_vector_type(8))) short  short8;   // 8 x bf16 (4 VGPRs)
typedef __attribute__((ext_vector_type(4))) float  floatx4;  // MFMA f32 acc

__device__ __forceinline__ ushort_t f2b(float f) {  // fp32 -> bf16 RNE
  union { float f; unsigned int u; } v; v.f = f;
  return (ushort_t)((v.u + 0x7FFFu + ((v.u >> 16) & 1u)) >> 16);
}
// pack two fp32 -> two bf16 (round-half-up)
__device__ __forceinline__ unsigned int pk2(float lo, float hi) {
  union { float f; unsigned int u; } a, b; a.f = lo; b.f = hi;
  return ((a.u + 0x8000u) >> 16) | ((b.u + 0x8000u) & 0xFFFF0000u);
}

// ---------------------------------------------------------------------------
// Kernel A: q[b,h,:] = seq1[b]@Wq_h + bq_h, then r[b,h,:] = (Wk_h @ q)/sqrt(D).
// r stored bf16, layout [b][h][e]. bk skipped (softmax-invariant shift).
// ---------------------------------------------------------------------------
__global__ __launch_bounds__(256) void qr_kernel(
    const float* __restrict__ seq1, const float* __restrict__ Wq,
    const float* __restrict__ bq,   const float* __restrict__ Wk,
    ushort_t* __restrict__ r_bf) {
  __shared__ __align__(16) float qp[4][64];
  __shared__ __align__(16) float qv[64];
  const int b = blockIdx.x / H_, h = blockIdx.x % H_;
  const int t = threadIdx.x;
  const int d = t & 63, quarter = t >> 6;

  {
    const float* s1 = seq1 + (size_t)b * E_;
    const float* wq = Wq + h * D_ + d;
    float sum = 0.f;
    const int e0 = quarter * 256;
    for (int e = e0; e < e0 + 256; ++e)
      sum += s1[e] * wq[(size_t)e * HD_];
    qp[quarter][d] = sum;
  }
  __syncthreads();
  if (t < 64) qv[t] = qp[0][t] + qp[1][t] + qp[2][t] + qp[3][t] + bq[h * D_ + t];
  __syncthreads();

  for (int i = 0; i < 4; ++i) {
    const int e = t + 256 * i;
    const float* wk = Wk + (size_t)e * HD_ + h * D_;
    float rs = 0.f;
#pragma unroll
    for (int g = 0; g < 16; ++g) {
      const float4 w4 = *(const float4*)(wk + g * 4);
      rs += w4.x * qv[g * 4 + 0] + w4.y * qv[g * 4 + 1] +
            w4.z * qv[g * 4 + 2] + w4.w * qv[g * 4 + 3];
    }
    r_bf[((size_t)b * H_ + h) * E_ + e] = f2b(rs * 0.125f);  // fold 1/sqrt(64)
  }
}

// ---------------------------------------------------------------------------
// Kernel B: flash pass over seq2, double-buffered.
//  - B-operand (r, all 16 heads) lives in 32 VGPRs per lane, loaded once.
//  - per 16-row tile: MFMA scores -> wave0 masked online-softmax -> VALU
//    outer-product accumulate (16h x 4e per thread); next tile's global loads
//    are issued before MFMA and converted/written to the other LDS buffer
//    after the accumulate -> loads always in flight (BW-bound).
// ---------------------------------------------------------------------------
__global__ __launch_bounds__(256, 2) void attn_kernel(
    const float* __restrict__ seq2, const int* __restrict__ mask,
    const ushort_t* __restrict__ r_bf, float* __restrict__ cpart,
    float* __restrict__ mlpart, int NC, int TPC) {
  __shared__ __align__(16) ushort_t xS[2][16][1032];  // X tiles, bf16 (+pad)
  __shared__ __align__(16) float scp[4][16][17];      // per-wave score partials
  __shared__ __align__(16) float Pt[16][16];          // p[s][h]
  __shared__ __align__(16) float mS[16], lS[16], alphaS[16];

  const int b = blockIdx.y, chunk = blockIdx.x;
  const int t = threadIdx.x;
  const int lane = t & 63, w = t >> 6;
  const int m = lane & 15, q = lane >> 4;
  const int s0 = chunk * (TPC * 16);
  const int e0 = t * 4;                  // this thread's 4 e-columns

  // loop-invariant B fragments: rf[kk][j] = r[h=m][e = w*256 + kk*32 + q*8 + j]
  short8 rf[8];
  {
    const ushort_t* rb = r_bf + ((size_t)b * H_ + m) * E_ + w * 256 + q * 8;
#pragma unroll
    for (int kk = 0; kk < 8; ++kk) rf[kk] = *(const short8*)(rb + kk * 32);
  }
  if (t < 16) { mS[t] = -3e38f; lS[t] = 0.f; }

  float c[16][4];
#pragma unroll
  for (int h = 0; h < 16; ++h)
#pragma unroll
    for (int j = 0; j < 4; ++j) c[h][j] = 0.f;

  // prologue: stage tile 0 into buffer 0
  float4 xr[16];
  {
    const float4* src = (const float4*)(seq2 + ((size_t)b * S_ + s0) * E_);
#pragma unroll
    for (int i = 0; i < 16; ++i) xr[i] = src[t + 256 * i];
#pragma unroll
    for (int i = 0; i < 16; ++i)
      *(uint2*)&xS[0][i][t * 4] =
          make_uint2(pk2(xr[i].x, xr[i].y), pk2(xr[i].z, xr[i].w));
  }
  __syncthreads();

  for (int it = 0; it < TPC; ++it) {
    const int p = it & 1;
    const int st = s0 + it * 16;
    const bool more = (it + 1 < TPC);

    // issue next tile's loads (no wait)
    if (more) {
      const float4* src =
          (const float4*)(seq2 + ((size_t)b * S_ + st + 16) * E_);
#pragma unroll
      for (int i = 0; i < 16; ++i) xr[i] = src[t + 256 * i];
    }
    // wave0 prefetches this tile's mask quad (consumed after sync)
    int4 mk;
    if (w == 0) mk = *(const int4*)&mask[(size_t)b * S_ + st + q * 4];

    // MFMA scores: wave w covers e in [w*256, w*256+256)
    {
      floatx4 acc = {0.f, 0.f, 0.f, 0.f};
#pragma unroll
      for (int kk = 0; kk < 8; ++kk) {
        const int kb = w * 256 + kk * 32 + q * 8;
        short8 av = *(const short8*)&xS[p][m][kb];  // A[m=s][k=e]
        acc = __builtin_amdgcn_mfma_f32_16x16x32_bf16(av, rf[kk], acc, 0, 0, 0);
      }
#pragma unroll
      for (int j = 0; j < 4; ++j)
        scp[w][q * 4 + j][m] = acc[j];  // C: col=m(=h), row=q*4+j(=s)
    }
    __syncthreads();

    // wave 0: reduce 4 K-partials, mask, online softmax, write P
    if (w == 0) {
      const int h = m, sg = q;
      const int mki[4] = {mk.x, mk.y, mk.z, mk.w};
      float sc[4];
#pragma unroll
      for (int j = 0; j < 4; ++j) {
        const int s = sg * 4 + j;
        float v = scp[0][s][h] + scp[1][s][h] + scp[2][s][h] + scp[3][s][h];
        if (mki[j] == 0) v = -1e9f;  // match reference
        sc[j] = v;
      }
      float tm = fmaxf(fmaxf(sc[0], sc[1]), fmaxf(sc[2], sc[3]));
      tm = fmaxf(tm, __shfl_xor(tm, 16));
      tm = fmaxf(tm, __shfl_xor(tm, 32));
      const float mo = mS[h];
      const float nm = fmaxf(mo, tm);
      const float al = __expf(mo - nm);
      float ps = 0.f;
#pragma unroll
      for (int j = 0; j < 4; ++j) {
        const float pj = __expf(sc[j] - nm);
        Pt[sg * 4 + j][h] = pj;
        ps += pj;
      }
      ps += __shfl_xor(ps, 16);
      ps += __shfl_xor(ps, 32);
      if (lane < 16) { mS[h] = nm; alphaS[h] = al; lS[h] = lS[h] * al + ps; }
    }
    __syncthreads();

    // accumulate: c[h][:] = c[h][:]*alpha[h] + sum_s P[s][h] * x[s][e0..e0+3]
    {
#pragma unroll
      for (int h = 0; h < 16; ++h) {
        const float a = alphaS[h];
        c[h][0] *= a; c[h][1] *= a; c[h][2] *= a; c[h][3] *= a;
      }
#pragma unroll
      for (int s = 0; s < 16; ++s) {
        union { uint2 v; ushort_t u[4]; } xv;
        xv.v = *(const uint2*)&xS[p][s][e0];
        union { unsigned int i; float f; } cv;
        cv.i = (unsigned int)xv.u[0] << 16; const float x0 = cv.f;
        cv.i = (unsigned int)xv.u[1] << 16; const float x1 = cv.f;
        cv.i = (unsigned int)xv.u[2] << 16; const float x2 = cv.f;
        cv.i = (unsigned int)xv.u[3] << 16; const float x3 = cv.f;
        float pv[16];
        *(float4*)&pv[0]  = *(const float4*)&Pt[s][0];
        *(float4*)&pv[4]  = *(const float4*)&Pt[s][4];
        *(float4*)&pv[8]  = *(const float4*)&Pt[s][8];
        *(float4*)&pv[12] = *(const float4*)&Pt[s][12];
#pragma unroll
        for (int h = 0; h < 16; ++h) {
          c[h][0] += pv[h] * x0; c[h][1] += pv[h] * x1;
          c[h][2] += pv[h] * x2; c[h][3] += pv[h] * x3;
        }
      }
    }

    // convert + write next tile into the other buffer (waits on loads here).
    // Safe without a pre-barrier: buf(p^1) was last read before the previous
    // iteration's closing barrier.
    if (more) {
#pragma unroll
      for (int i = 0; i < 16; ++i)
        *(uint2*)&xS[p ^ 1][i][t * 4] =
            make_uint2(pk2(xr[i].x, xr[i].y), pk2(xr[i].z, xr[i].w));
    }
    __syncthreads();
  }

  // write chunk partials: c (f32) and (m,l) per head
  const size_t base = ((size_t)b * NC + chunk) * H_ * E_;
#pragma unroll
  for (int h = 0; h < 16; ++h)
    *(float4*)&cpart[base + (size_t)h * E_ + e0] =
        make_float4(c[h][0], c[h][1], c[h][2], c[h][3]);
  if (t < 16) {  // wave0 lanes that wrote mS/lS themselves (no race)
    mlpart[(((size_t)b * NC + chunk) * H_ + t) * 2 + 0] = mS[t];
    mlpart[(((size_t)b * NC + chunk) * H_ + t) * 2 + 1] = lS[t];
  }
}

// ---------------------------------------------------------------------------
// Kernel C: combine chunk partials for one (b,h), then out = (c/L)@Wv_h + bv_h
// ---------------------------------------------------------------------------
__global__ __launch_bounds__(256) void combine_kernel(
    const float* __restrict__ cpart, const float* __restrict__ mlpart,
    const float* __restrict__ Wv, const float* __restrict__ bvp,
    float* __restrict__ out, int NC) {
  __shared__ __align__(16) float wS[64];
  __shared__ __align__(16) float cnS[1024];
  __shared__ __align__(16) float vp[4][64];
  __shared__ float invLS;
  const int b = blockIdx.x / H_, h = blockIdx.x % H_;
  const int t = threadIdx.x;

  if (t < 64) {
    float m_i = -3e38f, l_i = 0.f;
    if (t < NC) {
      const size_t mi = (((size_t)b * NC + t) * H_ + h) * 2;
      m_i = mlpart[mi]; l_i = mlpart[mi + 1];
    }
    float M = m_i;
#pragma unroll
    for (int dlt = 1; dlt < 64; dlt <<= 1) M = fmaxf(M, __shfl_xor(M, dlt));
    const float wi = (t < NC) ? __expf(m_i - M) : 0.f;
    float Lp = l_i * wi;
#pragma unroll
    for (int dlt = 1; dlt < 64; dlt <<= 1) Lp += __shfl_xor(Lp, dlt);
    if (t < NC) wS[t] = wi;
    if (t == 0) invLS = 1.f / Lp;
  }
  __syncthreads();

  {
    const int e0 = t * 4;
    float a0 = 0.f, a1 = 0.f, a2 = 0.f, a3 = 0.f;
    for (int i = 0; i < NC; ++i) {
      const float wi = wS[i];
      const float4 v =
          *(const float4*)&cpart[(((size_t)b * NC + i) * H_ + h) * E_ + e0];
      a0 += wi * v.x; a1 += wi * v.y; a2 += wi * v.z; a3 += wi * v.w;
    }
    const float inv = invLS;
    *(float4*)&cnS[e0] = make_float4(a0 * inv, a1 * inv, a2 * inv, a3 * inv);
  }
  __syncthreads();

  {
    const int n = t & 63, part = t >> 6;
    const float* wv = Wv + h * NV_ + n;
    float sum = 0.f;
    const int eb = part * 256;
    for (int e = eb; e < eb + 256; ++e)
      sum += cnS[e] * wv[(size_t)e * E_];
    vp[part][n] = sum;
  }
  __syncthreads();
  if (t < 64) {
    const float o = vp[0][t] + vp[1][t] + vp[2][t] + vp[3][t] + bvp[h * NV_ + t];
    out[(size_t)b * E_ + h * NV_ + t] = o;
  }
}

// ---------------------------------------------------------------------------
extern "C" void kernel_launch(void* const* d_in, const int* in_sizes, int n_in,
                              void* d_out, int out_size, void* d_ws, size_t ws_size,
                              hipStream_t stream) {
  const float* seq1 = (const float*)d_in[0];
  const float* seq2 = (const float*)d_in[1];
  const int*   mask = (const int*)d_in[2];
  const float* Wq   = (const float*)d_in[3];
  const float* bq   = (const float*)d_in[4];
  const float* Wk   = (const float*)d_in[5];
  // d_in[6] = bk: softmax-invariant, skipped
  const float* Wv   = (const float*)d_in[7];
  const float* bv   = (const float*)d_in[8];
  float* out = (float*)d_out;

  // workspace: r_bf (1 MB bf16) | cpart (B*NC*H*E f32) | mlpart
  const size_t rbytes = (size_t)B_ * H_ * E_ * 2;
  int NC = 32;  // 1024 attn blocks; combine assumes NC <= 64
  while (NC > 1) {
    const size_t need = rbytes + (size_t)B_ * NC * H_ * E_ * 4
                               + (size_t)B_ * NC * H_ * 2 * 4;
    if (need <= ws_size) break;
    NC >>= 1;
  }
  const int TPC = (S_ / NC) / 16;
  ushort_t* r_bf = (ushort_t*)d_ws;
  float* cpart   = (float*)((char*)d_ws + rbytes);
  float* mlpart  = (float*)((char*)d_ws + rbytes + (size_t)B_ * NC * H_ * E_ * 4);

  qr_kernel<<<dim3(B_ * H_), dim3(256), 0, stream>>>(seq1, Wq, bq, Wk, r_bf);
  attn_kernel<<<dim3(NC, B_), dim3(256), 0, stream>>>(seq2, mask, r_bf, cpart,
                                                      mlpart, NC, TPC);
  combine_kernel<<<dim3(B_ * H_), dim3(256), 0, stream>>>(cpart, mlpart, Wv, bv,
                                                          out, NC);
}